// Round 14
// baseline (78.854 us; speedup 1.0000x reference)
//
#include <hip/hip_runtime.h>
#include <hip/hip_cooperative_groups.h>

namespace cg = cooperative_groups;

// GCN 2-layer for MI355X. Primary path: single cooperative kernel (4 fused
// phases, grid.sync between). Fallback path (if cooperative launch is
// rejected -- r13 showed it erroring silently): the proven r12 four-kernel
// pipeline. Both paths identical math; choice is config-deterministic.
//
// record: src (bits 0..16) | local_dst (bits 17..23), NPB=128

#define NPB   128
#define NBSH  7
#define T     256       // fused kernel threads
#define EPT   16        // fused phase-1 edges/thread (epb=4093 <= 4096)
#define CAP   5120      // per-bucket capacity (mean 4092, sd 64; +16 sd)
#define LPN   8         // lanes per node in agg
#define FPAD  1024

// fallback (r12) geometry
#define NPARTF 512
#define PBSF   1024
#define EPTF   7
#define CBSF   512
#define ABSF   256

struct Ph1 { int hist[FPAD]; unsigned stage[T * EPT]; };
struct Ph2 { int offs[FPAD]; int fbase[FPAD]; unsigned raw[CAP]; };

__device__ __forceinline__ int block_exscan4(int v, int t, int* wsum) {
    __syncthreads();
    int lane = t & 63, wid = t >> 6;
    int inc = v;
#pragma unroll
    for (int off = 1; off < 64; off <<= 1) {
        int u = __shfl_up(inc, off);
        if (lane >= off) inc += u;
    }
    if (lane == 63) wsum[wid] = inc;
    __syncthreads();
    int wbase = 0;
    if (wid == 1)      wbase = wsum[0];
    else if (wid == 2) wbase = wsum[0] + wsum[1];
    else if (wid == 3) wbase = wsum[0] + wsum[1] + wsum[2];
    return inc - v + wbase;
}

// ======================= fused cooperative kernel =======================
__global__ __launch_bounds__(T, 4) void k_fused(
    const int* __restrict__ src, const int* __restrict__ dst,
    const float* __restrict__ x,
    const float* __restrict__ W1, const float* __restrict__ b1,
    const float* __restrict__ W2, const float* __restrict__ b2,
    int E, int n, int epb, int nbuck,
    int* __restrict__ offT, unsigned* __restrict__ packed,
    unsigned* __restrict__ sorted,
    float* __restrict__ p1g, float2* __restrict__ p2g,
    float2* __restrict__ out)
{
    cg::grid_group grid = cg::this_grid();
    __shared__ union { Ph1 a; Ph2 b; } u;
    __shared__ int wsum[4];
    __shared__ int s_bsize;
    __shared__ int nstart_l[NPB], deg_l[NPB], cur_l[NPB];
    __shared__ float dis_l[NPB], p1self[NPB];
    __shared__ float2 p2self[NPB];

    const int b = blockIdx.x, t = threadIdx.x;
    const int k = b;

    // phase 1: block-major bucket sort
    {
        const int lo = b * epb;
        const int blockEdges = max(0, min(epb, E - lo));
        for (int i = t; i < FPAD; i += T) u.a.hist[i] = 0;
        __syncthreads();
        unsigned rec[EPT]; int bkt[EPT];
#pragma unroll
        for (int it = 0; it < EPT; ++it) {
            int idx = it * T + t;
            bkt[it] = -1; rec[it] = 0;
            if (idx < blockEdges) {
                int d = dst[lo + idx], s = src[lo + idx];
                rec[it] = (unsigned)s | ((unsigned)(d & (NPB - 1)) << 17);
                bkt[it] = d >> NBSH;
                atomicAdd(&u.a.hist[bkt[it]], 1);
            }
        }
        __syncthreads();
        int j0 = 4 * t;
        int h0 = u.a.hist[j0], h1 = u.a.hist[j0 + 1],
            h2 = u.a.hist[j0 + 2], h3 = u.a.hist[j0 + 3];
        int ex = block_exscan4(h0 + h1 + h2 + h3, t, wsum);
        int e0 = ex, e1 = ex + h0, e2 = e1 + h1, e3 = e2 + h2;
        __syncthreads();
        u.a.hist[j0] = e0; u.a.hist[j0 + 1] = e1;
        u.a.hist[j0 + 2] = e2; u.a.hist[j0 + 3] = e3;
        if (j0 < nbuck)     offT[(size_t)b * nbuck + j0]     = e0;
        if (j0 + 1 < nbuck) offT[(size_t)b * nbuck + j0 + 1] = e1;
        if (j0 + 2 < nbuck) offT[(size_t)b * nbuck + j0 + 2] = e2;
        if (j0 + 3 < nbuck) offT[(size_t)b * nbuck + j0 + 3] = e3;
        __syncthreads();
#pragma unroll
        for (int it = 0; it < EPT; ++it)
            if (bkt[it] >= 0) {
                int pos = atomicAdd(&u.a.hist[bkt[it]], 1);
                u.a.stage[pos] = rec[it];
            }
        __syncthreads();
        for (int i = t; i < blockEdges; i += T)
            packed[(size_t)lo + i] = u.a.stage[i];
    }
    grid.sync();

    // phase 2: per-bucket node sort -> sorted; deg/dis/p1 (LDS-resident)
    {
        int f0 = 4 * t;
        int fo[4], fl[4];
#pragma unroll
        for (int i = 0; i < 4; ++i) {
            int f = f0 + i; fo[i] = 0; fl[i] = 0;
            if (f < nbuck) {
                int o = offT[(size_t)f * nbuck + k];
                int e = (k + 1 < nbuck) ? offT[(size_t)f * nbuck + k + 1]
                                        : max(0, min(epb, E - f * epb));
                fo[i] = o; fl[i] = e - o;
            }
        }
        int sum = fl[0] + fl[1] + fl[2] + fl[3];
        int ex = block_exscan4(sum, t, wsum);
        if (t == T - 1) s_bsize = min(ex + sum, CAP);
        u.b.offs[f0] = fo[0]; u.b.offs[f0 + 1] = fo[1];
        u.b.offs[f0 + 2] = fo[2]; u.b.offs[f0 + 3] = fo[3];
        u.b.fbase[f0] = ex; u.b.fbase[f0 + 1] = ex + fl[0];
        u.b.fbase[f0 + 2] = ex + fl[0] + fl[1];
        u.b.fbase[f0 + 3] = ex + fl[0] + fl[1] + fl[2];
        if (t < NPB) cur_l[t] = 0;
        __syncthreads();
        const int bsize = s_bsize;
        for (int fb = 0; fb < FPAD; fb += T / 4) {
            int f = fb + (t >> 2);
            if (f < nbuck) {
                int base = u.b.fbase[f];
                int nxt  = (f + 1 < FPAD) ? u.b.fbase[f + 1] : bsize;
                int len  = nxt - base;
                const unsigned* pp = packed + (size_t)f * epb + u.b.offs[f];
                for (int i = (t & 3); i < len; i += 4) {
                    int p = base + i;
                    if (p < CAP) u.b.raw[p] = pp[i];
                }
            }
        }
        __syncthreads();
        for (int i = t; i < bsize; i += T)
            atomicAdd(&cur_l[u.b.raw[i] >> 17], 1);
        __syncthreads();
        int myc = (t < NPB) ? cur_l[t] : 0;
        int cex = block_exscan4(myc, t, wsum);
        if (t < NPB) {
            nstart_l[t] = cex;
            deg_l[t]    = myc;
            cur_l[t]    = cex;
            int d = k * NPB + t;
            if (d < n) {
                float r = rsqrtf((float)(myc + 1));
                dis_l[t] = r;
                float pv = x[d] * r;
                p1self[t] = pv;
                p1g[d] = pv;
            }
        }
        __syncthreads();
        unsigned* sb = sorted + (size_t)k * CAP;
        for (int i = t; i < bsize; i += T) {
            unsigned r = u.b.raw[i];
            int pos = atomicAdd(&cur_l[r >> 17], 1);
            sb[pos] = r;
        }
    }
    grid.sync();

    // phase 3: layer-1 agg + fused MLP
    {
        const unsigned* sb = sorted + (size_t)k * CAP;
        const int lane = t & (LPN - 1);
#pragma unroll
        for (int pass = 0; pass < NPB / (T / LPN); ++pass) {
            int j = pass * (T / LPN) + (t >> 3);
            int d = k * NPB + j;
            if (d < n) {
                int s0 = nstart_l[j], e0 = s0 + deg_l[j];
                float acc = 0.f;
                int i = s0 + lane;
                for (; i + 3 * LPN < e0; i += 4 * LPN)
                    acc += p1g[sb[i] & 0x1FFFFu] + p1g[sb[i + LPN] & 0x1FFFFu]
                         + p1g[sb[i + 2 * LPN] & 0x1FFFFu]
                         + p1g[sb[i + 3 * LPN] & 0x1FFFFu];
                for (; i < e0; i += LPN) acc += p1g[sb[i] & 0x1FFFFu];
                acc += __shfl_xor(acc, 1);
                acc += __shfl_xor(acc, 2);
                acc += __shfl_xor(acc, 4);
                if (lane == 0) {
                    float r   = dis_l[j];
                    float agg = r * (acc + p1self[j]);
                    float c0 = 0.f, c1 = 0.f;
#pragma unroll
                    for (int q = 0; q < 16; ++q) {
                        float h = fmaxf(fmaf(agg, W1[q], b1[q]), 0.f);
                        c0 = fmaf(h, W2[2 * q],     c0);
                        c1 = fmaf(h, W2[2 * q + 1], c1);
                    }
                    float2 res = make_float2(c0 * r, c1 * r);
                    p2self[j] = res;
                    p2g[d] = res;
                }
            }
        }
    }
    grid.sync();

    // phase 4: layer-2 agg + fused log-softmax
    {
        const unsigned* sb = sorted + (size_t)k * CAP;
        const int lane = t & (LPN - 1);
#pragma unroll
        for (int pass = 0; pass < NPB / (T / LPN); ++pass) {
            int j = pass * (T / LPN) + (t >> 3);
            int d = k * NPB + j;
            if (d < n) {
                int s0 = nstart_l[j], e0 = s0 + deg_l[j];
                float c0 = 0.f, c1 = 0.f;
                int i = s0 + lane;
                for (; i + 3 * LPN < e0; i += 4 * LPN) {
                    float2 v0 = p2g[sb[i]           & 0x1FFFFu];
                    float2 v1 = p2g[sb[i + LPN]     & 0x1FFFFu];
                    float2 v2 = p2g[sb[i + 2 * LPN] & 0x1FFFFu];
                    float2 v3 = p2g[sb[i + 3 * LPN] & 0x1FFFFu];
                    c0 += v0.x + v1.x + v2.x + v3.x;
                    c1 += v0.y + v1.y + v2.y + v3.y;
                }
                for (; i < e0; i += LPN) {
                    float2 v = p2g[sb[i] & 0x1FFFFu];
                    c0 += v.x; c1 += v.y;
                }
                c0 += __shfl_xor(c0, 1); c0 += __shfl_xor(c0, 2); c0 += __shfl_xor(c0, 4);
                c1 += __shfl_xor(c1, 1); c1 += __shfl_xor(c1, 2); c1 += __shfl_xor(c1, 4);
                if (lane == 0) {
                    float r = dis_l[j];
                    float2 self = p2self[j];
                    float o0 = r * (c0 + self.x) + b2[0];
                    float o1 = r * (c1 + self.y) + b2[1];
                    float m  = fmaxf(o0, o1);
                    float ls = m + logf(expf(o0 - m) + expf(o1 - m));
                    out[d] = make_float2(o0 - ls, o1 - ls);
                }
            }
        }
    }
}

// ======================= fallback: r12 pipeline =======================
template <int NW>
__device__ __forceinline__ int block_exscanT(int v, int t, int* wsum) {
    int lane = t & 63, wid = t >> 6;
    int inc = v;
#pragma unroll
    for (int off = 1; off < 64; off <<= 1) {
        int u = __shfl_up(inc, off);
        if (lane >= off) inc += u;
    }
    if (lane == 63) wsum[wid] = inc;
    __syncthreads();
    if (wid == 0) {
        int w = (lane < NW) ? wsum[lane] : 0;
#pragma unroll
        for (int off = 1; off < NW; off <<= 1) {
            int u = __shfl_up(w, off);
            if (lane >= off) w += u;
        }
        if (lane < NW) wsum[lane] = w;
    }
    __syncthreads();
    return inc - v + (wid ? wsum[wid - 1] : 0);
}

__global__ __launch_bounds__(PBSF) void k_part(
    const int* __restrict__ src, const int* __restrict__ dst,
    int E, int epb, int nbuck,
    int* __restrict__ offT, unsigned* __restrict__ packed)
{
    __shared__ int s_scan[PBSF];
    __shared__ unsigned stage[PBSF * EPTF];
    __shared__ int wsum[PBSF / 64];
    const int b = blockIdx.x, t = threadIdx.x;
    const int lo = b * epb;
    int blockEdges = min(epb, E - lo); if (blockEdges < 0) blockEdges = 0;

    unsigned rec[EPTF]; int bkt[EPTF];
    s_scan[t] = 0;
    __syncthreads();
#pragma unroll
    for (int it = 0; it < EPTF; ++it) {
        int idx = it * PBSF + t;
        bkt[it] = -1; rec[it] = 0;
        if (idx < blockEdges) {
            int d = dst[lo + idx], s = src[lo + idx];
            rec[it] = (unsigned)s | ((unsigned)(d & (NPB - 1)) << 17);
            bkt[it] = d >> NBSH;
            atomicAdd(&s_scan[bkt[it]], 1);
        }
    }
    __syncthreads();
    int v = s_scan[t];
    __syncthreads();
    int excl = block_exscanT<PBSF / 64>(v, t, wsum);
    s_scan[t] = excl;
    if (t < nbuck) offT[(size_t)b * nbuck + t] = excl;
    __syncthreads();
#pragma unroll
    for (int it = 0; it < EPTF; ++it)
        if (bkt[it] >= 0) {
            int pos = atomicAdd(&s_scan[bkt[it]], 1);
            stage[pos] = rec[it];
        }
    __syncthreads();
    for (int i = t; i < blockEdges; i += PBSF)
        packed[(size_t)lo + i] = stage[i];
}

__global__ __launch_bounds__(CBSF) void k_csr(
    const unsigned* __restrict__ packed, const int* __restrict__ offT,
    const float* __restrict__ x,
    int E, int epb, int nbuck, int n,
    unsigned* __restrict__ sorted, int* __restrict__ nstart, int* __restrict__ nend,
    float* __restrict__ dis, float* __restrict__ p1)
{
    __shared__ unsigned raw[CAP];
    __shared__ int offs[NPARTF], fbase[NPARTF];
    __shared__ int cnt[NPB], cur[NPB];
    __shared__ int wsum[CBSF / 64];
    __shared__ int s_bsize;
    const int k = blockIdx.x, t = threadIdx.x;

    int o = offT[(size_t)t * nbuck + k];
    int e = (k + 1 < nbuck) ? offT[(size_t)t * nbuck + k + 1]
                            : max(0, min(epb, E - t * epb));
    int myflen = e - o;
    offs[t] = o;
    if (t < NPB) cnt[t] = 0;
    __syncthreads();
    int fexcl = block_exscanT<CBSF / 64>(myflen, t, wsum);
    fbase[t] = fexcl;
    if (t == CBSF - 1) s_bsize = min(fexcl + myflen, CAP);
    __syncthreads();
    const int bsize = s_bsize;
    for (int fb = 0; fb < NPARTF; fb += (CBSF >> 3)) {
        int f = fb + (t >> 3);
        const unsigned* pp = packed + (size_t)f * epb + offs[f];
        int base = fbase[f];
        int len  = ((f + 1 < NPARTF) ? fbase[f + 1] : bsize) - base;
        for (int i = (t & 7); i < len; i += 8) {
            int p = base + i;
            if (p < CAP) raw[p] = pp[i];
        }
    }
    __syncthreads();
    for (int i = t; i < bsize; i += CBSF)
        atomicAdd(&cnt[raw[i] >> 17], 1);
    __syncthreads();
    int myc = (t < NPB) ? cnt[t] : 0;
    __syncthreads();
    int cexcl = block_exscanT<CBSF / 64>(myc, t, wsum);
    if (t < NPB) {
        cur[t] = cexcl;
        int d = k * NPB + t;
        if (d < n) {
            int st = k * CAP + cexcl;
            nstart[d] = st;
            nend[d]   = min(st + myc, (k + 1) * CAP);
            float r = rsqrtf((float)(myc + 1));
            dis[d] = r;
            p1[d]  = x[d] * r;
        }
    }
    __syncthreads();
    for (int i = t; i < bsize; i += CBSF) {
        unsigned u = raw[i];
        int pos = k * CAP + atomicAdd(&cur[u >> 17], 1);
        sorted[pos] = u;
    }
}

__global__ __launch_bounds__(ABSF) void k_agg1(
    const unsigned* __restrict__ sorted,
    const int* __restrict__ nstart, const int* __restrict__ nend,
    const float* __restrict__ dis, const float* __restrict__ p1,
    const float* __restrict__ W1, const float* __restrict__ b1,
    const float* __restrict__ W2, int n, float2* __restrict__ p2)
{
    int gid = blockIdx.x * ABSF + threadIdx.x;
    int d = gid >> 3, lane = gid & (LPN - 1);
    if (d >= n) return;
    int s0 = nstart[d], e0 = nend[d];
    float acc = 0.f;
    int i = s0 + lane;
    for (; i + 3 * LPN < e0; i += 4 * LPN)
        acc += p1[sorted[i] & 0x1FFFFu] + p1[sorted[i + LPN] & 0x1FFFFu]
             + p1[sorted[i + 2 * LPN] & 0x1FFFFu]
             + p1[sorted[i + 3 * LPN] & 0x1FFFFu];
    for (; i < e0; i += LPN) acc += p1[sorted[i] & 0x1FFFFu];
    acc += __shfl_xor(acc, 1);
    acc += __shfl_xor(acc, 2);
    acc += __shfl_xor(acc, 4);
    if (lane == 0) {
        float r   = dis[d];
        float agg = r * (acc + p1[d]);
        float c0 = 0.f, c1 = 0.f;
#pragma unroll
        for (int j = 0; j < 16; ++j) {
            float h = fmaxf(fmaf(agg, W1[j], b1[j]), 0.f);
            c0 = fmaf(h, W2[2 * j],     c0);
            c1 = fmaf(h, W2[2 * j + 1], c1);
        }
        p2[d] = make_float2(c0 * r, c1 * r);
    }
}

__global__ __launch_bounds__(ABSF) void k_agg2(
    const unsigned* __restrict__ sorted,
    const int* __restrict__ nstart, const int* __restrict__ nend,
    const float* __restrict__ dis, const float2* __restrict__ p2,
    const float* __restrict__ b2, int n, float2* __restrict__ out)
{
    int gid = blockIdx.x * ABSF + threadIdx.x;
    int d = gid >> 3, lane = gid & (LPN - 1);
    if (d >= n) return;
    int s0 = nstart[d], e0 = nend[d];
    float c0 = 0.f, c1 = 0.f;
    int i = s0 + lane;
    for (; i + 3 * LPN < e0; i += 4 * LPN) {
        float2 v0 = p2[sorted[i]           & 0x1FFFFu];
        float2 v1 = p2[sorted[i + LPN]     & 0x1FFFFu];
        float2 v2 = p2[sorted[i + 2 * LPN] & 0x1FFFFu];
        float2 v3 = p2[sorted[i + 3 * LPN] & 0x1FFFFu];
        c0 += v0.x + v1.x + v2.x + v3.x;
        c1 += v0.y + v1.y + v2.y + v3.y;
    }
    for (; i < e0; i += LPN) {
        float2 v = p2[sorted[i] & 0x1FFFFu];
        c0 += v.x; c1 += v.y;
    }
    c0 += __shfl_xor(c0, 1); c0 += __shfl_xor(c0, 2); c0 += __shfl_xor(c0, 4);
    c1 += __shfl_xor(c1, 1); c1 += __shfl_xor(c1, 2); c1 += __shfl_xor(c1, 4);
    if (lane == 0) {
        float r = dis[d];
        float2 self = p2[d];
        float o0 = r * (c0 + self.x) + b2[0];
        float o1 = r * (c1 + self.y) + b2[1];
        float m  = fmaxf(o0, o1);
        float ls = m + logf(expf(o0 - m) + expf(o1 - m));
        out[d] = make_float2(o0 - ls, o1 - ls);
    }
}

extern "C" void kernel_launch(void* const* d_in, const int* in_sizes, int n_in,
                              void* d_out, int out_size, void* d_ws, size_t ws_size,
                              hipStream_t stream) {
    const float* x  = (const float*)d_in[0];
    const int*   ei = (const int*)d_in[1];
    const float* W1 = (const float*)d_in[2];
    const float* b1 = (const float*)d_in[3];
    const float* W2 = (const float*)d_in[4];
    const float* b2 = (const float*)d_in[5];

    int n = in_sizes[0];
    int E = in_sizes[1] / 2;
    const int* src = ei;
    const int* dst = ei + E;

    int nbuck = (n + NPB - 1) >> NBSH;           // 782
    int epbF  = (E + nbuck - 1) / nbuck;         // 4093 (fused)
    int epbP  = (E + NPARTF - 1) / NPARTF;       // 6250 (fallback)

    char* ws = (char*)d_ws;
    size_t off = 0;
    auto take = [&](size_t bytes) { char* p = ws + off; off += (bytes + 7) & ~(size_t)7; return p; };
    int*      offT   = (int*)take((size_t)nbuck * nbuck * 4);     // covers both paths
    unsigned* packed = (unsigned*)take((size_t)E * 4);
    unsigned* sorted = (unsigned*)take((size_t)nbuck * CAP * 4);
    int*      nstart = (int*)take((size_t)n * 4);
    int*      nend   = (int*)take((size_t)n * 4);
    float*    dis    = (float*)take((size_t)n * 4);
    float*    p1g    = (float*)take((size_t)n * 4);
    float2*   p2g    = (float2*)take((size_t)n * 8);
    float2*   outp   = (float2*)d_out;

    // Try the fused cooperative path only if occupancy guarantees co-residency.
    bool done = false;
    int dev = 0, cus = 0, occ = 0;
    (void)hipGetDevice(&dev);
    (void)hipDeviceGetAttribute(&cus, hipDeviceAttributeMultiprocessorCount, dev);
    hipError_t qe = hipOccupancyMaxActiveBlocksPerMultiprocessor(&occ, k_fused, T, 0);
    if (qe == hipSuccess && (long long)occ * cus >= nbuck) {
        void* args[] = {
            (void*)&src, (void*)&dst, (void*)&x, (void*)&W1, (void*)&b1,
            (void*)&W2, (void*)&b2, (void*)&E, (void*)&n, (void*)&epbF,
            (void*)&nbuck, (void*)&offT, (void*)&packed, (void*)&sorted,
            (void*)&p1g, (void*)&p2g, (void*)&outp
        };
        hipError_t le = hipLaunchCooperativeKernel((void*)k_fused, dim3(nbuck),
                                                   dim3(T), args, 0, stream);
        if (le == hipSuccess) done = true;
        else (void)hipGetLastError();            // clear sticky error
    } else {
        (void)hipGetLastError();
    }

    if (!done) {                                  // r12 proven pipeline
        const int gridAgg = ((size_t)n * LPN + ABSF - 1) / ABSF;
        k_part<<<NPARTF, PBSF, 0, stream>>>(src, dst, E, epbP, nbuck, offT, packed);
        k_csr <<<nbuck, CBSF, 0, stream>>>(packed, offT, x, E, epbP, nbuck, n,
                                           sorted, nstart, nend, dis, p1g);
        k_agg1<<<gridAgg, ABSF, 0, stream>>>(sorted, nstart, nend, dis, p1g,
                                             W1, b1, W2, n, p2g);
        k_agg2<<<gridAgg, ABSF, 0, stream>>>(sorted, nstart, nend, dis, p2g,
                                             b2, n, outp);
    }
}

// Round 15
// 76.678 us; speedup vs baseline: 1.0284x; 1.0284x over previous
//
#include <hip/hip_runtime.h>

// GCN 2-layer for MI355X — two-level counting sort to per-node CSR, then
// atomic-free register-reduction aggregation. (r12 structure; cooperative
// fusion removed after r14 showed it 5x slower + graph-capture-incompatible.)
// r15: NPB 128->256 (nbuck 391): 64B-coalesced csr fragments, halved offT.
//
// record: src (bits 0..16) | local_dst (bits 17..24), NPB=256

#define NPB    256
#define NBSH   8
#define NPART  512      // partition blocks
#define PBS    1024     // k_part threads
#define EPT    7        // edges/thread in k_part (epb=6250 <= 7168)
#define CAP    9728     // per-bucket capacity (mean 8184, sd ~90; +17 sd)
#define CBS    1024     // k_csr threads
#define ABS    256      // agg threads
#define LPN    8        // lanes per node in agg

// Block-wide exclusive scan via wave shuffles. NW = waves/block.
template <int NW>
__device__ __forceinline__ int block_exscan(int v, int t, int* wsum) {
    int lane = t & 63, wid = t >> 6;
    int inc = v;
#pragma unroll
    for (int off = 1; off < 64; off <<= 1) {
        int u = __shfl_up(inc, off);
        if (lane >= off) inc += u;
    }
    if (lane == 63) wsum[wid] = inc;
    __syncthreads();
    if (wid == 0) {
        int w = (lane < NW) ? wsum[lane] : 0;
#pragma unroll
        for (int off = 1; off < NW; off <<= 1) {
            int u = __shfl_up(w, off);
            if (lane >= off) w += u;
        }
        if (lane < NW) wsum[lane] = w;
    }
    __syncthreads();
    return inc - v + (wid ? wsum[wid - 1] : 0);
}

// ---- level 1: block-major bucket sort ----
__global__ __launch_bounds__(PBS) void k_part(
    const int* __restrict__ src, const int* __restrict__ dst,
    int E, int epb, int nbuck,
    int* __restrict__ offT, unsigned* __restrict__ packed)
{
    __shared__ int s_scan[PBS];
    __shared__ unsigned stage[PBS * EPT];
    __shared__ int wsum[PBS / 64];
    const int b = blockIdx.x, t = threadIdx.x;
    const int lo = b * epb;
    int blockEdges = min(epb, E - lo); if (blockEdges < 0) blockEdges = 0;

    unsigned rec[EPT]; int bkt[EPT];
    s_scan[t] = 0;
    __syncthreads();
#pragma unroll
    for (int it = 0; it < EPT; ++it) {
        int idx = it * PBS + t;
        bkt[it] = -1; rec[it] = 0;
        if (idx < blockEdges) {
            int d = dst[lo + idx], s = src[lo + idx];
            rec[it] = (unsigned)s | ((unsigned)(d & (NPB - 1)) << 17);
            bkt[it] = d >> NBSH;
            atomicAdd(&s_scan[bkt[it]], 1);
        }
    }
    __syncthreads();
    int v = s_scan[t];
    __syncthreads();
    int excl = block_exscan<PBS / 64>(v, t, wsum);
    s_scan[t] = excl;                          // reuse as cursors
    if (t < nbuck) offT[(size_t)b * nbuck + t] = excl;
    __syncthreads();
#pragma unroll
    for (int it = 0; it < EPT; ++it)
        if (bkt[it] >= 0) {
            int pos = atomicAdd(&s_scan[bkt[it]], 1);
            stage[pos] = rec[it];
        }
    __syncthreads();
    for (int i = t; i < blockEdges; i += PBS)
        packed[(size_t)lo + i] = stage[i];
}

// ---- level 2: per-bucket node-level sort -> CSR + deg/dis/p1 fused ----
__global__ __launch_bounds__(CBS) void k_csr(
    const unsigned* __restrict__ packed, const int* __restrict__ offT,
    const float* __restrict__ x,
    int E, int epb, int nbuck, int n,
    unsigned* __restrict__ sorted, int* __restrict__ nstart, int* __restrict__ nend,
    float* __restrict__ dis, float* __restrict__ p1)
{
    __shared__ unsigned raw[CAP];
    __shared__ int offs[NPART], fbase[NPART];
    __shared__ int cnt[NPB], cur[NPB];
    __shared__ int wsum[CBS / 64];
    __shared__ int s_bsize;
    const int k = blockIdx.x, t = threadIdx.x;

    int o = 0, myflen = 0;
    if (t < NPART) {
        o = offT[(size_t)t * nbuck + k];
        int e = (k + 1 < nbuck) ? offT[(size_t)t * nbuck + k + 1]
                                : max(0, min(epb, E - t * epb));
        myflen = e - o;
        offs[t] = o;
    }
    if (t < NPB) cnt[t] = 0;
    __syncthreads();
    int fexcl = block_exscan<CBS / 64>(myflen, t, wsum);
    if (t < NPART) fbase[t] = fexcl;
    if (t == NPART - 1) s_bsize = min(fexcl + myflen, CAP);
    __syncthreads();
    const int bsize = s_bsize;
    // gather fragments into raw[]: 16 contiguous lanes per fragment (64 B)
    for (int fb = 0; fb < NPART; fb += (CBS >> 4)) {
        int f = fb + (t >> 4);
        const unsigned* pp = packed + (size_t)f * epb + offs[f];
        int base = fbase[f];
        int len  = ((f + 1 < NPART) ? fbase[f + 1] : bsize) - base;
        for (int i = (t & 15); i < len; i += 16) {
            int p = base + i;
            if (p < CAP) raw[p] = pp[i];
        }
    }
    __syncthreads();
    // node-level count
    for (int i = t; i < bsize; i += CBS)
        atomicAdd(&cnt[raw[i] >> 17], 1);
    __syncthreads();
    int myc = (t < NPB) ? cnt[t] : 0;
    __syncthreads();
    int cexcl = block_exscan<CBS / 64>(myc, t, wsum);
    if (t < NPB) {
        cur[t] = cexcl;                        // cursor for scatter
        int d = k * NPB + t;
        if (d < n) {
            int st = k * CAP + cexcl;
            nstart[d] = st;
            nend[d]   = min(st + myc, (k + 1) * CAP);
            float r = rsqrtf((float)(myc + 1)); // +1 self-loop
            dis[d] = r;
            p1[d]  = x[d] * r;
        }
    }
    __syncthreads();
    // scatter into node-sorted order
    for (int i = t; i < bsize; i += CBS) {
        unsigned u = raw[i];
        int pos = k * CAP + atomicAdd(&cur[u >> 17], 1);
        sorted[pos] = u;
    }
}

// ---- layer 1: atomic-free segment reduce + fused MLP -> p2 ----
__global__ __launch_bounds__(ABS) void k_agg1(
    const unsigned* __restrict__ sorted,
    const int* __restrict__ nstart, const int* __restrict__ nend,
    const float* __restrict__ dis, const float* __restrict__ p1,
    const float* __restrict__ W1, const float* __restrict__ b1,
    const float* __restrict__ W2, int n, float2* __restrict__ p2)
{
    int gid = blockIdx.x * ABS + threadIdx.x;
    int d = gid >> 3, lane = gid & (LPN - 1);
    if (d >= n) return;
    int s0 = nstart[d], e0 = nend[d];
    float acc = 0.f;
    int i = s0 + lane;
    for (; i + 3 * LPN < e0; i += 4 * LPN) {   // 4 independent gathers in flight
        acc += p1[sorted[i] & 0x1FFFFu] + p1[sorted[i + LPN] & 0x1FFFFu]
             + p1[sorted[i + 2 * LPN] & 0x1FFFFu]
             + p1[sorted[i + 3 * LPN] & 0x1FFFFu];
    }
    for (; i < e0; i += LPN) acc += p1[sorted[i] & 0x1FFFFu];
    acc += __shfl_xor(acc, 1);
    acc += __shfl_xor(acc, 2);
    acc += __shfl_xor(acc, 4);
    if (lane == 0) {
        float r   = dis[d];
        float agg = r * (acc + p1[d]);          // + self-loop
        float c0 = 0.f, c1 = 0.f;
#pragma unroll
        for (int j = 0; j < 16; ++j) {
            float h = fmaxf(fmaf(agg, W1[j], b1[j]), 0.f);
            c0 = fmaf(h, W2[2 * j],     c0);
            c1 = fmaf(h, W2[2 * j + 1], c1);
        }
        p2[d] = make_float2(c0 * r, c1 * r);    // prescaled by dis[src]
    }
}

// ---- layer 2: atomic-free segment reduce + fused log-softmax -> out ----
__global__ __launch_bounds__(ABS) void k_agg2(
    const unsigned* __restrict__ sorted,
    const int* __restrict__ nstart, const int* __restrict__ nend,
    const float* __restrict__ dis, const float2* __restrict__ p2,
    const float* __restrict__ b2, int n, float2* __restrict__ out)
{
    int gid = blockIdx.x * ABS + threadIdx.x;
    int d = gid >> 3, lane = gid & (LPN - 1);
    if (d >= n) return;
    int s0 = nstart[d], e0 = nend[d];
    float c0 = 0.f, c1 = 0.f;
    int i = s0 + lane;
    for (; i + 3 * LPN < e0; i += 4 * LPN) {   // 4 gathers in flight
        float2 v0 = p2[sorted[i]           & 0x1FFFFu];
        float2 v1 = p2[sorted[i + LPN]     & 0x1FFFFu];
        float2 v2 = p2[sorted[i + 2 * LPN] & 0x1FFFFu];
        float2 v3 = p2[sorted[i + 3 * LPN] & 0x1FFFFu];
        c0 += v0.x + v1.x + v2.x + v3.x;
        c1 += v0.y + v1.y + v2.y + v3.y;
    }
    for (; i < e0; i += LPN) {
        float2 v = p2[sorted[i] & 0x1FFFFu];
        c0 += v.x; c1 += v.y;
    }
    c0 += __shfl_xor(c0, 1); c0 += __shfl_xor(c0, 2); c0 += __shfl_xor(c0, 4);
    c1 += __shfl_xor(c1, 1); c1 += __shfl_xor(c1, 2); c1 += __shfl_xor(c1, 4);
    if (lane == 0) {
        float r = dis[d];
        float2 self = p2[d];
        float o0 = r * (c0 + self.x) + b2[0];
        float o1 = r * (c1 + self.y) + b2[1];
        float m  = fmaxf(o0, o1);
        float ls = m + logf(expf(o0 - m) + expf(o1 - m));
        out[d] = make_float2(o0 - ls, o1 - ls);
    }
}

extern "C" void kernel_launch(void* const* d_in, const int* in_sizes, int n_in,
                              void* d_out, int out_size, void* d_ws, size_t ws_size,
                              hipStream_t stream) {
    const float* x  = (const float*)d_in[0];
    const int*   ei = (const int*)d_in[1];     // int32 [2, E]
    const float* W1 = (const float*)d_in[2];
    const float* b1 = (const float*)d_in[3];
    const float* W2 = (const float*)d_in[4];
    const float* b2 = (const float*)d_in[5];

    const int n = in_sizes[0];                 // 100000
    const int E = in_sizes[1] / 2;             // 3200000
    const int* src = ei;
    const int* dst = ei + E;

    const int nbuck = (n + NPB - 1) >> NBSH;   // 391
    const int epb   = (E + NPART - 1) / NPART; // 6250

    char* ws = (char*)d_ws;
    size_t off = 0;
    auto take = [&](size_t bytes) { char* p = ws + off; off += (bytes + 7) & ~(size_t)7; return p; };
    int*      offT   = (int*)take((size_t)NPART * nbuck * 4);     // 0.8 MB
    unsigned* packed = (unsigned*)take((size_t)E * 4);            // 12.8 MB
    unsigned* sorted = (unsigned*)take((size_t)nbuck * CAP * 4);  // 15.2 MB
    int*      nstart = (int*)take((size_t)n * 4);
    int*      nend   = (int*)take((size_t)n * 4);
    float*    dis    = (float*)take((size_t)n * 4);
    float*    p1     = (float*)take((size_t)n * 4);
    float2*   p2     = (float2*)take((size_t)n * 8);

    const int gridAgg = ((size_t)n * LPN + ABS - 1) / ABS;        // 3125

    k_part<<<NPART, PBS, 0, stream>>>(src, dst, E, epb, nbuck, offT, packed);
    k_csr <<<nbuck, CBS, 0, stream>>>(packed, offT, x, E, epb, nbuck, n,
                                      sorted, nstart, nend, dis, p1);
    k_agg1<<<gridAgg, ABS, 0, stream>>>(sorted, nstart, nend, dis, p1,
                                        W1, b1, W2, n, p2);
    k_agg2<<<gridAgg, ABS, 0, stream>>>(sorted, nstart, nend, dis, p2,
                                        b2, n, (float2*)d_out);
}